// Round 3
// baseline (258.789 us; speedup 1.0000x reference)
//
#include <hip/hip_runtime.h>
#include <stdint.h>

#define NB 8
#define NC 8
#define NN 1024
#define ND 256
#define KK 2048      // NC * ND
#define BM 128
#define BN 128
#define BKK 64
#define NT (KK / BKK)

typedef float f32x4 __attribute__((ext_vector_type(4)));
typedef short bf16x8 __attribute__((ext_vector_type(8)));

__device__ __forceinline__ unsigned short f2bf(float x) {
  union { float f; uint32_t u; } a; a.f = x;
  uint32_t u = a.u;
  return (unsigned short)((u + 0x7FFFu + ((u >> 16) & 1u)) >> 16);  // RTNE
}

__device__ __forceinline__ void gload16(const void* g, void* l) {
  __builtin_amdgcn_global_load_lds(
      (__attribute__((address_space(1))) uint32_t*)g,
      (__attribute__((address_space(3))) uint32_t*)l, 16, 0, 0);
}

// Pass 1: per (b,c,n) row of 256: sq = sum g^2, rnorm = rsqrt(sum g^4);
// write ghat[b][n][c*256+d] = bf16(g * rnorm); uv[b*N+n][c]=sq*rnorm, [8+c]=rnorm.
__global__ __launch_bounds__(256) void prep_kernel(
    const float* __restrict__ g, unsigned short* __restrict__ ghat,
    float* __restrict__ uv) {
  int wid = blockIdx.x * 4 + (threadIdx.x >> 6);   // wave id, 4 rows per wave
  int lane = threadIdx.x & 63;
#pragma unroll
  for (int j = 0; j < 4; ++j) {
    int rowid = wid * 4 + j;                       // (b,c,n) flat row
    int n = rowid & (NN - 1);
    int bc = rowid >> 10;
    int c = bc & (NC - 1);
    int b = bc >> 3;
    const float* row = g + (size_t)rowid * ND;
    f32x4 v = *(const f32x4*)(row + lane * 4);
    float s2 = 0.f, s4 = 0.f;
#pragma unroll
    for (int q = 0; q < 4; ++q) { float x2 = v[q] * v[q]; s2 += x2; s4 += x2 * x2; }
#pragma unroll
    for (int off = 32; off; off >>= 1) {
      s2 += __shfl_xor(s2, off);
      s4 += __shfl_xor(s4, off);
    }
    float rn = rsqrtf(s4);
    ushort4 o;
    o.x = f2bf(v[0] * rn); o.y = f2bf(v[1] * rn);
    o.z = f2bf(v[2] * rn); o.w = f2bf(v[3] * rn);
    size_t gh = ((size_t)(b * NN + n)) * KK + (size_t)c * ND + lane * 4;
    *(ushort4*)(ghat + gh) = o;
    if (lane == 0) {
      size_t uvo = ((size_t)(b * NN + n)) * 16;
      uv[uvo + c] = s2 * rn;       // u
      uv[uvo + 8 + c] = rn;        // v
    }
  }
}

// Stage one 128x64 tile as 16 fragment-ordered 1KB blocks (block = i*2+kk,
// i = 16-row group, kk = 32-elem k-half). LDS dest is linear-in-lane (the
// canonical conflict-free pattern); the per-lane GLOBAL source does the
// fragment gather: lane l -> row i*16+(l&15), k-chunk (l>>4)*8.
// Each wave stages 4 of the 16 blocks.
__device__ __forceinline__ void stage_tile_frag(const unsigned short* __restrict__ gsrc,
                                                unsigned short* lds, int k0,
                                                int wave, int lane) {
#pragma unroll
  for (int t = 0; t < 4; ++t) {
    int blk = wave * 4 + t;
    int i = blk >> 1;
    int kk = blk & 1;
    gload16(gsrc + (size_t)(i * 16 + (lane & 15)) * KK + k0 + kk * 32 + (lane >> 4) * 8,
            lds + blk * 512 + lane * 8);
  }
}

// Pass 2: per b, out = 0.125*(u_n.v_m + v_n.u_m) - 0.25 * <ghat_n, ghat_m>
__global__ __launch_bounds__(256) void gram_gemm_kernel(
    const unsigned short* __restrict__ ghat, const float* __restrict__ uv,
    float* __restrict__ out) {
  __shared__ union {
    struct { unsigned short A[2][16 * 512]; unsigned short Bt[2][16 * 512]; } s;  // 64 KiB
    struct { float R[128][16]; float Cc[128][16]; } e;                            // 16 KiB
  } sm;

  // XCD-aware swizzle: 512 blocks, 8 XCDs -> 64 consecutive logical tiles
  // (= one batch b, one 4MiB ghat panel) per XCD L2.
  int bid = blockIdx.x;
  int logical = (bid & 7) * (NB * 64 / 8) + (bid >> 3);
  int b = logical >> 6;
  int t6 = logical & 63;
  int row0 = (t6 >> 3) * BM;
  int col0 = (t6 & 7) * BN;
  int tid = threadIdx.x;
  int lane = tid & 63;
  int wave = tid >> 6;
  int wr = (wave >> 1) * 64;    // 2x2 wave grid, 64x64 per wave
  int wc = (wave & 1) * 64;
  int ab0 = (wr >> 4) * 2;      // first A fragment-block this wave consumes
  int bb0 = (wc >> 4) * 2;

  const unsigned short* gA = ghat + (size_t)(b * NN + row0) * KK;
  const unsigned short* gB = ghat + (size_t)(b * NN + col0) * KK;

  f32x4 acc[4][4];
#pragma unroll
  for (int i = 0; i < 4; ++i)
#pragma unroll
    for (int j = 0; j < 4; ++j)
      acc[i][j] = f32x4{0.f, 0.f, 0.f, 0.f};

  // prologue: stage tile 0 into buf 0
  stage_tile_frag(gA, sm.s.A[0], 0, wave, lane);
  stage_tile_frag(gB, sm.s.Bt[0], 0, wave, lane);
  __syncthreads();              // vmcnt(0) drained: buf0 ready

  int cur = 0;
  for (int t = 0; t < NT; ++t) {
    if (t + 1 < NT) {           // issue next-tile loads BEFORE compute (overlap)
      stage_tile_frag(gA, sm.s.A[cur ^ 1], (t + 1) * BKK, wave, lane);
      stage_tile_frag(gB, sm.s.Bt[cur ^ 1], (t + 1) * BKK, wave, lane);
    }
#pragma unroll
    for (int kk = 0; kk < 2; ++kk) {
      bf16x8 af[4], bfb[4];
#pragma unroll
      for (int i = 0; i < 4; ++i)
        af[i] = *(const bf16x8*)&sm.s.A[cur][((ab0 + i * 2 + kk) * 512) + lane * 8];
#pragma unroll
      for (int j = 0; j < 4; ++j)
        bfb[j] = *(const bf16x8*)&sm.s.Bt[cur][((bb0 + j * 2 + kk) * 512) + lane * 8];
#pragma unroll
      for (int i = 0; i < 4; ++i)
#pragma unroll
        for (int j = 0; j < 4; ++j)
          acc[i][j] = __builtin_amdgcn_mfma_f32_16x16x32_bf16(af[i], bfb[j], acc[i][j], 0, 0, 0);
    }
    __syncthreads();            // one drain+barrier per K-step (T3 2-phase)
    cur ^= 1;
  }

  // Stage u/v rows+cols into (reused) LDS: 2048 contiguous floats each side.
  {
    const f32x4* srcR = (const f32x4*)(uv + (size_t)(b * NN + row0) * 16);
    const f32x4* srcC = (const f32x4*)(uv + (size_t)(b * NN + col0) * 16);
    f32x4* dR = (f32x4*)&sm.e.R[0][0];
    f32x4* dC = (f32x4*)&sm.e.Cc[0][0];
#pragma unroll
    for (int i = 0; i < 2; ++i) {
      dR[tid + i * 256] = srcR[tid + i * 256];
      dC[tid + i * 256] = srcC[tid + i * 256];
    }
  }
  __syncthreads();

  int lr = (lane >> 4) * 4;
  int lc = lane & 15;
#pragma unroll
  for (int j = 0; j < 4; ++j) {
    int cl = wc + j * 16 + lc;
    f32x4 uc0 = *(const f32x4*)&sm.e.Cc[cl][0];
    f32x4 uc1 = *(const f32x4*)&sm.e.Cc[cl][4];
    f32x4 vc0 = *(const f32x4*)&sm.e.Cc[cl][8];
    f32x4 vc1 = *(const f32x4*)&sm.e.Cc[cl][12];
#pragma unroll
    for (int i = 0; i < 4; ++i) {
#pragma unroll
      for (int q = 0; q < 4; ++q) {
        int rl = wr + i * 16 + lr + q;
        f32x4 r0 = *(const f32x4*)&sm.e.R[rl][0];
        f32x4 r1 = *(const f32x4*)&sm.e.R[rl][4];
        f32x4 r2 = *(const f32x4*)&sm.e.R[rl][8];
        f32x4 r3 = *(const f32x4*)&sm.e.R[rl][12];
        float fr = r0[0]*vc0[0]+r0[1]*vc0[1]+r0[2]*vc0[2]+r0[3]*vc0[3]
                 + r1[0]*vc1[0]+r1[1]*vc1[1]+r1[2]*vc1[2]+r1[3]*vc1[3]
                 + r2[0]*uc0[0]+r2[1]*uc0[1]+r2[2]*uc0[2]+r2[3]*uc0[3]
                 + r3[0]*uc1[0]+r3[1]*uc1[1]+r3[2]*uc1[2]+r3[3]*uc1[3];
        float val = 0.125f * fr - 0.25f * acc[i][j][q];
        out[((size_t)(b * NN + row0 + rl)) * NN + (size_t)(col0 + cl)] = val;
      }
    }
  }
}

extern "C" void kernel_launch(void* const* d_in, const int* in_sizes, int n_in,
                              void* d_out, int out_size, void* d_ws, size_t ws_size,
                              hipStream_t stream) {
  const float* g = (const float*)d_in[0];
  // d_in[1] = patchPerRow (unused by the reference computation)
  unsigned short* ghat = (unsigned short*)d_ws;                         // 32 MiB bf16
  float* uv = (float*)((char*)d_ws + (size_t)NB * NN * KK * 2);         // 512 KiB f32
  float* outp = (float*)d_out;

  prep_kernel<<<NB * NC * NN / 16, 256, 0, stream>>>(g, ghat, uv);
  gram_gemm_kernel<<<NB * 64, 256, 0, stream>>>(ghat, uv, outp);
}

// Round 4
// 210.895 us; speedup vs baseline: 1.2271x; 1.2271x over previous
//
#include <hip/hip_runtime.h>
#include <stdint.h>

#define NB 8
#define NC 8
#define NN 1024
#define ND 256
#define KK 2048      // NC * ND
#define BM 128
#define BN 64
#define BKK 64
#define NT (KK / BKK)

typedef float f32x4 __attribute__((ext_vector_type(4)));
typedef short bf16x8 __attribute__((ext_vector_type(8)));

__device__ __forceinline__ unsigned short f2bf(float x) {
  union { float f; uint32_t u; } a; a.f = x;
  uint32_t u = a.u;
  return (unsigned short)((u + 0x7FFFu + ((u >> 16) & 1u)) >> 16);  // RTNE
}

__device__ __forceinline__ void gload16(const void* g, void* l) {
  __builtin_amdgcn_global_load_lds(
      (__attribute__((address_space(1))) uint32_t*)g,
      (__attribute__((address_space(3))) uint32_t*)l, 16, 0, 0);
}

// Pass 1: per (b,c,n) row of 256: sq = sum g^2, rnorm = rsqrt(sum g^4);
// ghat[b][n][c*256+d] = bf16(g * rnorm); uFlat[rowid]=sq*rnorm, vFlat[rowid]=rnorm.
// Flat u/v: one cacheline is written by ONE wave (consecutive rowids), no
// cross-XCD cacheline sharing (the old [node][16] AoS had 8 XCD writers/line).
__global__ __launch_bounds__(256) void prep_kernel(
    const float* __restrict__ g, unsigned short* __restrict__ ghat,
    float* __restrict__ uFlat, float* __restrict__ vFlat) {
  int wid = blockIdx.x * 4 + (threadIdx.x >> 6);   // wave id, 4 rows per wave
  int lane = threadIdx.x & 63;
#pragma unroll
  for (int j = 0; j < 4; ++j) {
    int rowid = wid * 4 + j;                       // (b,c,n) flat row
    int n = rowid & (NN - 1);
    int bc = rowid >> 10;
    int c = bc & (NC - 1);
    int b = bc >> 3;
    const float* row = g + (size_t)rowid * ND;
    f32x4 v = *(const f32x4*)(row + lane * 4);
    float s2 = 0.f, s4 = 0.f;
#pragma unroll
    for (int q = 0; q < 4; ++q) { float x2 = v[q] * v[q]; s2 += x2; s4 += x2 * x2; }
#pragma unroll
    for (int off = 32; off; off >>= 1) {
      s2 += __shfl_xor(s2, off);
      s4 += __shfl_xor(s4, off);
    }
    float rn = rsqrtf(s4);
    ushort4 o;
    o.x = f2bf(v[0] * rn); o.y = f2bf(v[1] * rn);
    o.z = f2bf(v[2] * rn); o.w = f2bf(v[3] * rn);
    size_t gh = ((size_t)(b * NN + n)) * KK + (size_t)c * ND + lane * 4;
    *(ushort4*)(ghat + gh) = o;
    if (lane == 0) {
      uFlat[rowid] = s2 * rn;
      vFlat[rowid] = rn;
    }
  }
}

// Pass 2: per b, out = 0.125*(u_n.v_m + v_n.u_m) - 0.25 * <ghat_n, ghat_m>
// Single-buffered 24KiB LDS (m97 2-barrier loop), 1024 blocks -> 4-5/CU for
// inter-block latency hiding. Both-sides XOR slot swizzle (R1-proven).
__global__ __launch_bounds__(256) void gram_gemm_kernel(
    const unsigned short* __restrict__ ghat,
    const float* __restrict__ uFlat, const float* __restrict__ vFlat,
    float* __restrict__ out) {
  __shared__ union {
    struct { unsigned short A[BM * BKK]; unsigned short Bt[BN * BKK]; } s;  // 24 KiB
    struct { float R[128][16]; float Cc[64][16]; } e;                       // 12 KiB
  } sm;

  // XCD swizzle: 1024 blocks, 8 XCDs -> 128 consecutive logical tiles
  // (= one full batch b, one 4MiB ghat panel) per XCD L2.
  int bid = blockIdx.x;
  int logical = (bid & 7) * 128 + (bid >> 3);
  int b = logical >> 7;
  int t7 = logical & 127;
  int row0 = (t7 >> 4) * BM;   // 8 row tiles
  int col0 = (t7 & 15) * BN;   // 16 col tiles
  int tid = threadIdx.x;
  int lane = tid & 63;
  int wave = tid >> 6;
  int wr = (wave >> 1) * 64;   // 2x2 wave grid: 64x32 out per wave
  int wc = (wave & 1) * 32;

  const unsigned short* gA = ghat + (size_t)(b * NN + row0) * KK;
  const unsigned short* gB = ghat + (size_t)(b * NN + col0) * KK;

  f32x4 acc[4][2];
#pragma unroll
  for (int i = 0; i < 4; ++i)
#pragma unroll
    for (int j = 0; j < 2; ++j)
      acc[i][j] = f32x4{0.f, 0.f, 0.f, 0.f};

  int rsel = lane & 15;        // fragment row selector
  int khalf = lane >> 4;       // k-quarter selector
  int r8 = tid >> 3;           // staging row within 32-row group (0..31)
  int s8 = tid & 7;            // staging 16B slot (0..7)

  for (int t = 0; t < NT; ++t) {
    int k0 = t * BKK;
    // stage A (128 rows) + B (64 rows), pre-swizzled global slot
#pragma unroll
    for (int i = 0; i < 4; ++i) {
      int rr = i * 32 + r8;
      int sg = s8 ^ (rr & 7);
      gload16(gA + (size_t)rr * KK + k0 + sg * 8, sm.s.A + rr * BKK + s8 * 8);
    }
#pragma unroll
    for (int i = 0; i < 2; ++i) {
      int rr = i * 32 + r8;
      int sg = s8 ^ (rr & 7);
      gload16(gB + (size_t)rr * KK + k0 + sg * 8, sm.s.Bt + rr * BKK + s8 * 8);
    }
    __syncthreads();           // drains vmcnt(0): tile ready
#pragma unroll
    for (int kk = 0; kk < 2; ++kk) {
      bf16x8 af[4], bfb[2];
#pragma unroll
      for (int i = 0; i < 4; ++i) {
        int rr = wr + i * 16 + rsel;
        int slot = (kk * 4 + khalf) ^ (rr & 7);
        af[i] = *(const bf16x8*)&sm.s.A[rr * BKK + slot * 8];
      }
#pragma unroll
      for (int j = 0; j < 2; ++j) {
        int rr = wc + j * 16 + rsel;
        int slot = (kk * 4 + khalf) ^ (rr & 7);
        bfb[j] = *(const bf16x8*)&sm.s.Bt[rr * BKK + slot * 8];
      }
#pragma unroll
      for (int i = 0; i < 4; ++i)
#pragma unroll
        for (int j = 0; j < 2; ++j)
          acc[i][j] = __builtin_amdgcn_mfma_f32_16x16x32_bf16(af[i], bfb[j], acc[i][j], 0, 0, 0);
    }
    __syncthreads();           // protect LDS before next stage
  }

  // Gather u/v (flat layout) into LDS: R[rl][0..7]=u_row, [8..15]=v_row;
  // Cc[cl][0..7]=u_col, [8..15]=v_col.
  {
    int rl = tid >> 1;                 // 0..127
    int half = tid & 1;                // 0 = u, 1 = v
    const float* src = half ? vFlat : uFlat;
#pragma unroll
    for (int c = 0; c < 8; ++c)
      sm.e.R[rl][half * 8 + c] = src[(size_t)(b * NC + c) * NN + row0 + rl];
    if (rl < 64) {
#pragma unroll
      for (int c = 0; c < 8; ++c)
        sm.e.Cc[rl][half * 8 + c] = src[(size_t)(b * NC + c) * NN + col0 + rl];
    }
  }
  __syncthreads();

  int lr = (lane >> 4) * 4;
  int lc = lane & 15;
#pragma unroll
  for (int j = 0; j < 2; ++j) {
    int cl = wc + j * 16 + lc;
    f32x4 uc0 = *(const f32x4*)&sm.e.Cc[cl][0];
    f32x4 uc1 = *(const f32x4*)&sm.e.Cc[cl][4];
    f32x4 vc0 = *(const f32x4*)&sm.e.Cc[cl][8];
    f32x4 vc1 = *(const f32x4*)&sm.e.Cc[cl][12];
#pragma unroll
    for (int i = 0; i < 4; ++i) {
#pragma unroll
      for (int q = 0; q < 4; ++q) {
        int rl = wr + i * 16 + lr + q;
        f32x4 r0 = *(const f32x4*)&sm.e.R[rl][0];
        f32x4 r1 = *(const f32x4*)&sm.e.R[rl][4];
        f32x4 r2 = *(const f32x4*)&sm.e.R[rl][8];
        f32x4 r3 = *(const f32x4*)&sm.e.R[rl][12];
        float fr = r0[0]*vc0[0]+r0[1]*vc0[1]+r0[2]*vc0[2]+r0[3]*vc0[3]
                 + r1[0]*vc1[0]+r1[1]*vc1[1]+r1[2]*vc1[2]+r1[3]*vc1[3]
                 + r2[0]*uc0[0]+r2[1]*uc0[1]+r2[2]*uc0[2]+r2[3]*uc0[3]
                 + r3[0]*uc1[0]+r3[1]*uc1[1]+r3[2]*uc1[2]+r3[3]*uc1[3];
        float val = 0.125f * fr - 0.25f * acc[i][j][q];
        out[((size_t)(b * NN + row0 + rl)) * NN + (size_t)(col0 + cl)] = val;
      }
    }
  }
}

extern "C" void kernel_launch(void* const* d_in, const int* in_sizes, int n_in,
                              void* d_out, int out_size, void* d_ws, size_t ws_size,
                              hipStream_t stream) {
  const float* g = (const float*)d_in[0];
  // d_in[1] = patchPerRow (unused by the reference computation)
  unsigned short* ghat = (unsigned short*)d_ws;                          // 32 MiB bf16
  float* uFlat = (float*)((char*)d_ws + (size_t)NB * NN * KK * 2);       // 256 KiB
  float* vFlat = uFlat + (size_t)NB * NC * NN;                           // 256 KiB
  float* outp = (float*)d_out;

  prep_kernel<<<NB * NC * NN / 16, 256, 0, stream>>>(g, ghat, uFlat, vFlat);
  gram_gemm_kernel<<<NB * 128 * 8 / 8 /* =1024 */, 256, 0, stream>>>(ghat, uFlat, vFlat, outp);
}